// Round 3
// baseline (584.750 us; speedup 1.0000x reference)
//
#include <hip/hip_runtime.h>
#include <stdint.h>

// Cross-attention fused block, MI355X/gfx950. Round 3.
// - attn v2: 32x32x16 MFMA, 32 q/wave, Q in regs (B-operand), KVBLK=32,
//   grouped-8 K/V layouts (conflict-free ds_read_b128), LDS double-buffer with
//   stage-before-compute (T3-lite), defer-max (T13), XCD-swizzled grid.
// - GEMMs: double-buffered LDS, stage(t+1) issued before compute(t).
// - mask: ballot pack to u32[m/32][q] (coalesced both in pack and in attn).

#define H_ 8
#define N_ 4096
#define M_ 4096
#define F_ 1024
#define D_ 256

typedef unsigned short u16;
typedef unsigned int u32;
typedef unsigned long long u64;
typedef unsigned char u8;
typedef __bf16 bf16x8 __attribute__((ext_vector_type(8)));
typedef float f32x4 __attribute__((ext_vector_type(4)));
typedef float f32x16 __attribute__((ext_vector_type(16)));

static __device__ __forceinline__ u16 f2bf(float f) {
  union { float f; u32 u; } v; v.f = f;
  u32 u = v.u + 0x7fffu + ((v.u >> 16) & 1u);
  return (u16)(u >> 16);
}

static __device__ __forceinline__ u32 cvtpk(float lo, float hi) {
  u32 r;
  asm("v_cvt_pk_bf16_f32 %0, %1, %2" : "=v"(r) : "v"(lo), "v"(hi));
  return r;
}

static __device__ __forceinline__ void gld16(const void* g, void* l) {
  __builtin_amdgcn_global_load_lds(
      (const __attribute__((address_space(1))) void*)g,
      (__attribute__((address_space(3))) void*)l, 16, 0, 0);
}

// ---------------- mask dtype detect + ballot bit-pack ----------------
__global__ void k_mask_detect(const u32* __restrict__ m, u32* __restrict__ flag) {
  u32 bad = 0;
  for (int i = threadIdx.x; i < 4096; i += 64) bad |= (m[i] & ~1u);
  u64 anyBad = __ballot(bad != 0);
  if (threadIdx.x == 0) *flag = (anyBad != 0) ? 1u : 0u;
}

// out[mtile][q]: bit (m&31) of out[(m>>5)*N + q] = mask[q][m]. One wave per
// (q, 64-m segment): coalesced 256B (int32) / 64B (int8) read + ballot.
__global__ void k_mask_pack2(const void* __restrict__ mp, const u32* __restrict__ flag,
                             u32* __restrict__ out) {
  const int lane = threadIdx.x & 63, wave = threadIdx.x >> 6;
  const int wid = blockIdx.x * 4 + wave;
  const int qrow = wid >> 6;
  const int m0 = (wid & 63) * 64;
  int x;
  if (*flag) x = ((const u8*)mp)[(size_t)qrow * M_ + m0 + lane];
  else       x = ((const int*)mp)[(size_t)qrow * M_ + m0 + lane];
  u64 bits = __ballot(x != 0);
  if (lane == 0) {
    out[(size_t)(m0 >> 5) * N_ + qrow] = (u32)bits;
    out[(size_t)((m0 >> 5) + 1) * N_ + qrow] = (u32)(bits >> 32);
  }
}

// ---------------- f32 -> bf16 elementwise (vectorized) ----------------
__global__ void k_f32_to_bf16(const float* __restrict__ in, u16* __restrict__ out, int n4) {
  int i = blockIdx.x * blockDim.x + threadIdx.x;
  if (i >= n4) return;
  float4 v = ((const float4*)in)[i];
  u32 w0 = (u32)f2bf(v.x) | ((u32)f2bf(v.y) << 16);
  u32 w1 = (u32)f2bf(v.z) | ((u32)f2bf(v.w) << 16);
  ((uint2*)out)[i] = make_uint2(w0, w1);
}

// ------------- transpose-convert f32 [b][R][C] -> bf16 [b][C][R] -------------
__global__ void k_transpose_f32_bf16(const float* __restrict__ in, u16* __restrict__ out,
                                     int R, int C) {
  __shared__ float t[32][33];
  const int b = blockIdx.z;
  const float* src = in + (size_t)b * R * C;
  u16* dst = out + (size_t)b * R * C;
  const int r0 = blockIdx.x * 32, c0 = blockIdx.y * 32;
  const int tr = threadIdx.x >> 3, tc = (threadIdx.x & 7) * 4;
  float4 v = *(const float4*)(src + (size_t)(r0 + tr) * C + c0 + tc);
  t[tr][tc + 0] = v.x; t[tr][tc + 1] = v.y; t[tr][tc + 2] = v.z; t[tr][tc + 3] = v.w;
  __syncthreads();
  u16* d4 = dst + (size_t)(c0 + tr) * R + r0 + tc;
  d4[0] = f2bf(t[tc + 0][tr]); d4[1] = f2bf(t[tc + 1][tr]);
  d4[2] = f2bf(t[tc + 2][tr]); d4[3] = f2bf(t[tc + 3][tr]);
}

// ---------------- NT GEMM, double-buffered (T3-lite) ----------------
// C[row][col] = sum_k A[row][k]*Bt[col][k]. 128x128 tile, BK=64, 4 waves,
// 16x16x32 bf16 MFMA, global_load_lds + XOR swizzle.
// EPI 0: natural bf16 [z][row][ldc]+bias  (q projection)
// EPI 1: kt2 layout  [z][d>>3][m][d&7]    (k projection; d=col, m=row)
// EPI 2: vt2 layout  [z][m>>3][d][m&7]    (v projection)
// EPI 3: f32 natural + bias + resid       (output projection)
template <int EPI>
__global__ __launch_bounds__(256, 2) void k_gemm_nt(
    const u16* __restrict__ A, const u16* __restrict__ B,
    const float* __restrict__ bias, const float* __restrict__ resid,
    u16* __restrict__ Cb, float* __restrict__ Cf,
    int K, int lda, int ldb, int ldc,
    size_t aBatch, size_t bBatch, size_t biasBatch, size_t cBatch)
{
  __shared__ u16 la[2][128 * 64];
  __shared__ u16 lb[2][128 * 64];
  const int tid = threadIdx.x;
  const int lane = tid & 63, wave = tid >> 6;
  const int g = lane >> 4, fr = lane & 15;
  const int wr = wave >> 1, wc = wave & 1;
  const int z = blockIdx.z;
  const size_t row0 = (size_t)blockIdx.x * 128, col0 = (size_t)blockIdx.y * 128;
  const u16* Ab = A + z * aBatch + row0 * lda;
  const u16* Bb = B + z * bBatch + col0 * ldb;

  f32x4 zero = {0.f, 0.f, 0.f, 0.f};
  f32x4 acc[4][4];
#pragma unroll
  for (int m = 0; m < 4; ++m)
#pragma unroll
    for (int n = 0; n < 4; ++n) acc[m][n] = zero;

  auto STAGE = [&](int bs, int k0) {
#pragma unroll
    for (int i = 0; i < 4; ++i) {
      int c = i * 256 + tid;
      int row = c >> 3, slot = c & 7;
      int srcSlot = slot ^ (row & 7);
      gld16(Ab + (size_t)row * lda + k0 + srcSlot * 8, &la[bs][(i * 256 + wave * 64) * 8]);
      gld16(Bb + (size_t)row * ldb + k0 + srcSlot * 8, &lb[bs][(i * 256 + wave * 64) * 8]);
    }
  };

  STAGE(0, 0);
  __syncthreads();
  int cur = 0;
  for (int k0 = 0; k0 < K; k0 += 64) {
    if (k0 + 64 < K) STAGE(cur ^ 1, k0 + 64);
    const char* lac = (const char*)la[cur];
    const char* lbc = (const char*)lb[cur];
#pragma unroll
    for (int kk = 0; kk < 2; ++kk) {
      const int colByte = (kk * 32 + g * 8) * 2;
      bf16x8 af[4], bfr[4];
#pragma unroll
      for (int m = 0; m < 4; ++m) {
        int row = wr * 64 + m * 16 + fr;
        af[m] = *(const bf16x8*)(lac + ((row * 128 + colByte) ^ ((row & 7) << 4)));
      }
#pragma unroll
      for (int n = 0; n < 4; ++n) {
        int row = wc * 64 + n * 16 + fr;
        bfr[n] = *(const bf16x8*)(lbc + ((row * 128 + colByte) ^ ((row & 7) << 4)));
      }
#pragma unroll
      for (int m = 0; m < 4; ++m)
#pragma unroll
        for (int n = 0; n < 4; ++n)
          acc[m][n] = __builtin_amdgcn_mfma_f32_16x16x32_bf16(af[m], bfr[n], acc[m][n], 0, 0, 0);
    }
    __syncthreads();
    cur ^= 1;
  }

#pragma unroll
  for (int n = 0; n < 4; ++n) {
    const int col = wc * 64 + n * 16 + fr;
    const float bv = bias[z * biasBatch + col0 + col];
#pragma unroll
    for (int m = 0; m < 4; ++m) {
#pragma unroll
      for (int r = 0; r < 4; ++r) {
        const int row = wr * 64 + m * 16 + g * 4 + r;
        const float val = acc[m][n][r] + bv;
        const size_t grow = row0 + row, gcol = col0 + col;
        if (EPI == 0) {
          Cb[(size_t)z * cBatch + grow * ldc + gcol] = f2bf(val);
        } else if (EPI == 1) {
          Cb[(size_t)z * (M_ * D_) + (gcol >> 3) * (M_ * 8) + grow * 8 + (gcol & 7)] = f2bf(val);
        } else if (EPI == 2) {
          Cb[(size_t)z * (M_ * D_) + (grow >> 3) * (D_ * 8) + gcol * 8 + (grow & 7)] = f2bf(val);
        } else {
          Cf[grow * ldc + gcol] = val + resid[grow * ldc + gcol];
        }
      }
    }
  }
}

// ---------------- flash attention v2 ----------------
// 256 blocks (bid&7 = head -> XCD-local K/V), 4 waves x 32 q-rows.
// MFMA 32x32x16. Swapped QK^T: s'[m][q] = mfma(A=K, B=Q). Lane: col=q=lane&31,
// hi=lane>>5. s reg r -> m=(r&3)+8*(r>>2)+4*hi. KVBLK=32, double-buffered LDS.
// K in LDS grouped [d>>3][m][d&7]; V grouped [m>>3][d][m&7]: every ds_read_b128
// is contiguous across lanes (conflict-free).
__global__ __launch_bounds__(256, 2) void k_attn2(
    const u16* __restrict__ q, const u16* __restrict__ k2,
    const u16* __restrict__ v2, const u32* __restrict__ mw,
    u16* __restrict__ cat)
{
  __shared__ u16 smem[32768];  // 64 KB = 2 buf x (16KB K + 16KB V)
  const int tid = threadIdx.x;
  const int lane = tid & 63, wave = tid >> 6;
  const int hi = lane >> 5, col = lane & 31;
  const int h = blockIdx.x & 7;
  const int xt = blockIdx.x >> 3;
  const int n0w = xt * 128 + wave * 32;
  const float L2E = 1.44269504f;

  const u16* kh = k2 + (size_t)h * (M_ * D_);
  const u16* vh = v2 + (size_t)h * (M_ * D_);

  // Q fragments (B-operand): col=lane&31 -> q-row, k = hi*8+j
  bf16x8 qf[16];
  {
    const u16* qp = q + ((size_t)h * N_ + n0w + col) * D_ + hi * 8;
#pragma unroll
    for (int dc = 0; dc < 16; ++dc) qf[dc] = *(const bf16x8*)(qp + dc * 16);
  }

  f32x16 racc[8];
#pragma unroll
  for (int i = 0; i < 8; ++i)
#pragma unroll
    for (int e = 0; e < 16; ++e) racc[i][e] = 0.f;

  float mrow = -3e38f, lrow = 0.f;
  const bool useMask = (h >= 4);
  const u32* mp = mw + (n0w + col);

  auto STAGE = [&](int bs, int m0) {
    u16* lkb = smem + bs * 16384;
    u16* lvb = lkb + 8192;
#pragma unroll
    for (int i = 0; i < 4; ++i) {
      int c = i * 256 + tid;
      // K chunk: dg=c>>5 (d-group), ml=c&31 (m)
      gld16(kh + (size_t)(c >> 5) * (M_ * 8) + (size_t)(m0 + (c & 31)) * 8,
            lkb + (i * 256 + wave * 64) * 8);
      // V chunk: mg=c>>8 (m-group), d=c&255
      gld16(vh + (size_t)(c >> 8) * (D_ * 8) + (size_t)m0 * 256 + (size_t)(c & 255) * 8,
            lvb + (i * 256 + wave * 64) * 8);
    }
  };

  STAGE(0, 0);
  __syncthreads();
  int cur = 0;

  for (int it = 0; it < M_ / 32; ++it) {
    const int m0 = it * 32;
    if (it + 1 < M_ / 32) STAGE(cur ^ 1, m0 + 32);
    u32 mword = 0xFFFFFFFFu;
    if (useMask) mword = mp[(size_t)(m0 >> 5) * N_];

    const char* lkb = (const char*)smem + cur * 32768;
    const char* lvb = lkb + 16384;

    // ---- QK^T: s'[m=32][q=32], K=256 over 16 MFMA (2 accumulator chains) ----
    f32x16 sA, sB;
#pragma unroll
    for (int e = 0; e < 16; ++e) { sA[e] = 0.f; sB[e] = 0.f; }
#pragma unroll
    for (int dc = 0; dc < 16; dc += 2) {
      bf16x8 a0 = *(const bf16x8*)(lkb + dc * 1024 + lane * 16);
      bf16x8 a1 = *(const bf16x8*)(lkb + dc * 1024 + 1024 + lane * 16);
      sA = __builtin_amdgcn_mfma_f32_32x32x16_bf16(a0, qf[dc], sA, 0, 0, 0);
      sB = __builtin_amdgcn_mfma_f32_32x32x16_bf16(a1, qf[dc + 1], sB, 0, 0, 0);
    }
    f32x16 sv = sA + sB;

    if (useMask) {
      u32 mm = mword >> (hi * 4);
#pragma unroll
      for (int r = 0; r < 16; ++r)
        if (!((mm >> ((r & 3) + 8 * (r >> 2))) & 1u)) sv[r] -= 1e9f;
    }

    // ---- online softmax (row q=col; halves hold disjoint m) ----
    float pm = sv[0];
#pragma unroll
    for (int r = 1; r < 16; ++r) pm = fmaxf(pm, sv[r]);
    pm = fmaxf(pm, __shfl_xor(pm, 32));

    if (!__all(pm <= mrow + 8.f)) {          // T13 defer-max
      float mnew = fmaxf(mrow, pm);
      float rs = __builtin_exp2f((mrow - mnew) * L2E);
      lrow *= rs;
#pragma unroll
      for (int i = 0; i < 8; ++i)
#pragma unroll
        for (int e = 0; e < 16; ++e) racc[i][e] *= rs;
      mrow = mnew;
    }
    const float mL = mrow * L2E;
    float p[16];
    float ls = 0.f;
#pragma unroll
    for (int r = 0; r < 16; ++r) {
      p[r] = __builtin_exp2f(sv[r] * L2E - mL);
      ls += p[r];
    }
    ls += __shfl_xor(ls, 32);
    lrow += ls;

    // ---- PV: racc[d][q] += V'^T . P^T  (B-frag built in-register) ----
#pragma unroll
    for (int ks = 0; ks < 2; ++ks) {
      u32 a0 = cvtpk(p[8 * ks + 0], p[8 * ks + 1]);
      u32 a1 = cvtpk(p[8 * ks + 2], p[8 * ks + 3]);
      u32 b0 = cvtpk(p[8 * ks + 4], p[8 * ks + 5]);
      u32 b1 = cvtpk(p[8 * ks + 6], p[8 * ks + 7]);
      u32 sa0 = __shfl_xor(a0, 32), sa1 = __shfl_xor(a1, 32);
      u32 sb0 = __shfl_xor(b0, 32), sb1 = __shfl_xor(b1, 32);
      union { u32 w[4]; bf16x8 v; } bp;
      bp.w[0] = hi ? sb0 : a0;
      bp.w[1] = hi ? sb1 : a1;
      bp.w[2] = hi ? b0 : sa0;
      bp.w[3] = hi ? b1 : sa1;
      const char* lvk = lvb + ks * 8192 + hi * 4096 + col * 16;
#pragma unroll
      for (int ds = 0; ds < 8; ++ds) {
        bf16x8 av = *(const bf16x8*)(lvk + ds * 512);
        racc[ds] = __builtin_amdgcn_mfma_f32_32x32x16_bf16(av, bp.v, racc[ds], 0, 0, 0);
      }
    }
    __syncthreads();
    cur ^= 1;
  }

  // ---- epilogue: normalize, LDS transpose (swizzled), coalesced store ----
  char* lt = (char*)smem + wave * 16384;  // per-wave [32 q][256 d] bf16
  const float inv = 1.f / lrow;
#pragma unroll
  for (int ds = 0; ds < 8; ++ds) {
#pragma unroll
    for (int t = 0; t < 8; ++t) {
      int d0 = ds * 32 + (2 * t & 3) + 8 * (t >> 1) + 4 * hi;
      u32 w = cvtpk(racc[ds][2 * t] * inv, racc[ds][2 * t + 1] * inv);
      *(u32*)(lt + ((col * 512 + d0 * 2) ^ ((col & 7) << 4))) = w;
    }
  }
  __syncthreads();
#pragma unroll
  for (int pch = 0; pch < 16; ++pch) {
    int c = pch * 64 + lane;
    int row = c >> 5, ch = c & 31;
    uint4 val = *(const uint4*)(lt + ((row * 512 + ch * 16) ^ ((row & 7) << 4)));
    *(uint4*)(cat + (size_t)(n0w + row) * (H_ * D_) + (size_t)h * D_ + ch * 8) = val;
  }
}

// ---------------- host launcher ----------------
extern "C" void kernel_launch(void* const* d_in, const int* in_sizes, int n_in,
                              void* d_out, int out_size, void* d_ws, size_t ws_size,
                              hipStream_t stream) {
  const float* thisf = (const float*)d_in[0];
  const float* thatf = (const float*)d_in[1];
  const void* maskp = (const void*)d_in[2];
  const float* Wq = (const float*)d_in[3];
  const float* bq = (const float*)d_in[4];
  const float* Wk = (const float*)d_in[5];
  const float* bk = (const float*)d_in[6];
  const float* Wv = (const float*)d_in[7];
  const float* bv = (const float*)d_in[8];
  const float* Wo = (const float*)d_in[9];
  const float* bo = (const float*)d_in[10];
  float* outp = (float*)d_out;

  char* ws = (char*)d_ws;
  size_t o = 0;
  u16* thisb = (u16*)(ws + o); o += (size_t)N_ * F_ * 2;
  u16* thatb = (u16*)(ws + o); o += (size_t)M_ * F_ * 2;
  u16* wqt = (u16*)(ws + o); o += (size_t)H_ * D_ * F_ * 2;
  u16* wkt = (u16*)(ws + o); o += (size_t)H_ * D_ * F_ * 2;
  u16* wvt = (u16*)(ws + o); o += (size_t)H_ * D_ * F_ * 2;
  u16* wot = (u16*)(ws + o); o += (size_t)F_ * 2 * F_ * 2;
  u16* qb  = (u16*)(ws + o); o += (size_t)H_ * N_ * D_ * 2;
  u16* k2  = (u16*)(ws + o); o += (size_t)H_ * M_ * D_ * 2;
  u16* v2  = (u16*)(ws + o); o += (size_t)H_ * M_ * D_ * 2;
  u16* catb = (u16*)(ws + o); o += (size_t)N_ * 2 * F_ * 2;
  u32* mw2 = (u32*)(ws + o); o += (size_t)(M_ / 32) * N_ * 4;
  u32* mflag = (u32*)(ws + o); o += 256;
  (void)ws_size; (void)in_sizes; (void)n_in; (void)out_size;

  // 0) mask: detect dtype, ballot-pack to [m/32][q]
  k_mask_detect<<<dim3(1), dim3(64), 0, stream>>>((const u32*)maskp, mflag);
  k_mask_pack2<<<dim3(N_ * (M_ / 64) / 4), dim3(256), 0, stream>>>(maskp, mflag, mw2);

  // 1) dtype conversions
  k_f32_to_bf16<<<dim3(N_ * F_ / 4 / 256), dim3(256), 0, stream>>>(thisf, thisb, N_ * F_ / 4);
  k_f32_to_bf16<<<dim3(M_ * F_ / 4 / 256), dim3(256), 0, stream>>>(thatf, thatb, M_ * F_ / 4);
  k_transpose_f32_bf16<<<dim3(F_ / 32, D_ / 32, H_), dim3(256), 0, stream>>>(Wq, wqt, F_, D_);
  k_transpose_f32_bf16<<<dim3(F_ / 32, D_ / 32, H_), dim3(256), 0, stream>>>(Wk, wkt, F_, D_);
  k_transpose_f32_bf16<<<dim3(F_ / 32, D_ / 32, H_), dim3(256), 0, stream>>>(Wv, wvt, F_, D_);
  k_transpose_f32_bf16<<<dim3(2 * F_ / 32, F_ / 32, 1), dim3(256), 0, stream>>>(Wo, wot, 2 * F_, F_);

  // 2) projections (k -> kt2 layout, v -> vt2 layout; q natural)
  k_gemm_nt<0><<<dim3(N_ / 128, D_ / 128, H_), dim3(256), 0, stream>>>(
      thisb, wqt, bq, nullptr, qb, nullptr, F_, F_, F_, D_,
      (size_t)0, (size_t)D_ * F_, (size_t)D_, (size_t)N_ * D_);
  k_gemm_nt<1><<<dim3(M_ / 128, D_ / 128, H_), dim3(256), 0, stream>>>(
      thatb, wkt, bk, nullptr, k2, nullptr, F_, F_, F_, D_,
      (size_t)0, (size_t)D_ * F_, (size_t)D_, (size_t)0);
  k_gemm_nt<2><<<dim3(M_ / 128, D_ / 128, H_), dim3(256), 0, stream>>>(
      thatb, wvt, bv, nullptr, v2, nullptr, F_, F_, F_, D_,
      (size_t)0, (size_t)D_ * F_, (size_t)D_, (size_t)0);

  // 3) flash attention v2 -> cat [N][H*D] bf16
  k_attn2<<<dim3(256), dim3(256), 0, stream>>>(qb, k2, v2, mw2, catb);

  // 4) out = cat @ Wo + bo + this   (f32 out)
  k_gemm_nt<3><<<dim3(N_ / 128, F_ / 128, 1), dim3(256), 0, stream>>>(
      catb, wot, bo, thisf, nullptr, outp, 2 * F_, 2 * F_, 2 * F_, F_,
      (size_t)0, (size_t)0, (size_t)0, (size_t)0);
}

// Round 5
// 511.205 us; speedup vs baseline: 1.1439x; 1.1439x over previous
//
#include <hip/hip_runtime.h>
#include <stdint.h>

// Cross-attention fused block, MI355X/gfx950. Round 5 (= round 4, re-audited;
// round 4 never ran due to GPU broker timeout).
// - attn: KV-split x2 (512 blocks -> 2 blocks/CU, 8 waves/CU), f16 normalized
//   partials + f32 (m,l), merge kernel. Grouped-8 K/V LDS layouts (conflict-free),
//   dbuf stage-before-compute, defer-max, XCD-head-local grid.
// - k&v projections fused into ONE GEMM (B = [wkt|wvt], 1024 blocks, 4/CU).
// - partial buffer aliases dead conversion buffers (ws high-water ~102.5 MB).

#define H_ 8
#define N_ 4096
#define M_ 4096
#define F_ 1024
#define D_ 256

typedef unsigned short u16;
typedef unsigned int u32;
typedef unsigned long long u64;
typedef unsigned char u8;
typedef __bf16 bf16x8 __attribute__((ext_vector_type(8)));
typedef float f32x4 __attribute__((ext_vector_type(4)));
typedef float f32x16 __attribute__((ext_vector_type(16)));

static __device__ __forceinline__ u16 f2bf(float f) {
  union { float f; u32 u; } v; v.f = f;
  u32 u = v.u + 0x7fffu + ((v.u >> 16) & 1u);
  return (u16)(u >> 16);
}

static __device__ __forceinline__ u32 cvtpk(float lo, float hi) {
  u32 r;
  asm("v_cvt_pk_bf16_f32 %0, %1, %2" : "=v"(r) : "v"(lo), "v"(hi));
  return r;
}

static __device__ __forceinline__ void gld16(const void* g, void* l) {
  __builtin_amdgcn_global_load_lds(
      (const __attribute__((address_space(1))) void*)g,
      (__attribute__((address_space(3))) void*)l, 16, 0, 0);
}

// ---------------- mask dtype detect + ballot bit-pack ----------------
__global__ void k_mask_detect(const u32* __restrict__ m, u32* __restrict__ flag) {
  u32 bad = 0;
  for (int i = threadIdx.x; i < 4096; i += 64) bad |= (m[i] & ~1u);
  u64 anyBad = __ballot(bad != 0);
  if (threadIdx.x == 0) *flag = (anyBad != 0) ? 1u : 0u;
}

// out[mtile][q]: bit (m&31) of out[(m>>5)*N + q] = mask[q][m].
__global__ void k_mask_pack2(const void* __restrict__ mp, const u32* __restrict__ flag,
                             u32* __restrict__ out) {
  const int lane = threadIdx.x & 63, wave = threadIdx.x >> 6;
  const int wid = blockIdx.x * 4 + wave;
  const int qrow = wid >> 6;
  const int m0 = (wid & 63) * 64;
  int x;
  if (*flag) x = ((const u8*)mp)[(size_t)qrow * M_ + m0 + lane];
  else       x = ((const int*)mp)[(size_t)qrow * M_ + m0 + lane];
  u64 bits = __ballot(x != 0);
  if (lane == 0) {
    out[(size_t)(m0 >> 5) * N_ + qrow] = (u32)bits;
    out[(size_t)((m0 >> 5) + 1) * N_ + qrow] = (u32)(bits >> 32);
  }
}

// ---------------- f32 -> bf16 elementwise ----------------
__global__ void k_f32_to_bf16(const float* __restrict__ in, u16* __restrict__ out, int n4) {
  int i = blockIdx.x * blockDim.x + threadIdx.x;
  if (i >= n4) return;
  float4 v = ((const float4*)in)[i];
  u32 w0 = (u32)f2bf(v.x) | ((u32)f2bf(v.y) << 16);
  u32 w1 = (u32)f2bf(v.z) | ((u32)f2bf(v.w) << 16);
  ((uint2*)out)[i] = make_uint2(w0, w1);
}

// ------------- transpose-convert f32 [b][R][C] -> bf16 [b][C][R] -------------
__global__ void k_transpose_f32_bf16(const float* __restrict__ in, u16* __restrict__ out,
                                     int R, int C) {
  __shared__ float t[32][33];
  const int b = blockIdx.z;
  const float* src = in + (size_t)b * R * C;
  u16* dst = out + (size_t)b * R * C;
  const int r0 = blockIdx.x * 32, c0 = blockIdx.y * 32;
  const int tr = threadIdx.x >> 3, tc = (threadIdx.x & 7) * 4;
  float4 v = *(const float4*)(src + (size_t)(r0 + tr) * C + c0 + tc);
  t[tr][tc + 0] = v.x; t[tr][tc + 1] = v.y; t[tr][tc + 2] = v.z; t[tr][tc + 3] = v.w;
  __syncthreads();
  u16* d4 = dst + (size_t)(c0 + tr) * R + r0 + tc;
  d4[0] = f2bf(t[tc + 0][tr]); d4[1] = f2bf(t[tc + 1][tr]);
  d4[2] = f2bf(t[tc + 2][tr]); d4[3] = f2bf(t[tc + 3][tr]);
}

// ---------------- NT GEMM, double-buffered ----------------
// EPI 0: natural bf16 [z][row][ldc]+bias       (q projection, z-batched)
// EPI 3: f32 natural + bias + resid            (output projection)
// EPI 4: fused kv: col<2048 -> k2 grouped [h][d>>3][m][d&7] (+bias=bk)
//        col>=2048 -> v2 grouped [h][m>>3][d][m&7] (+bv passed via resid)
template <int EPI>
__global__ __launch_bounds__(256, 2) void k_gemm_nt(
    const u16* __restrict__ A, const u16* __restrict__ B,
    const float* __restrict__ bias, const float* __restrict__ resid,
    u16* __restrict__ Cb, float* __restrict__ Cf,
    int K, int lda, int ldb, int ldc,
    size_t aBatch, size_t bBatch, size_t biasBatch, size_t cBatch)
{
  __shared__ u16 la[2][128 * 64];
  __shared__ u16 lb[2][128 * 64];
  const int tid = threadIdx.x;
  const int lane = tid & 63, wave = tid >> 6;
  const int g = lane >> 4, fr = lane & 15;
  const int wr = wave >> 1, wc = wave & 1;
  const int z = blockIdx.z;
  const size_t row0 = (size_t)blockIdx.x * 128, col0 = (size_t)blockIdx.y * 128;
  const u16* Ab = A + z * aBatch + row0 * lda;
  const u16* Bb = B + z * bBatch + col0 * ldb;

  f32x4 zero = {0.f, 0.f, 0.f, 0.f};
  f32x4 acc[4][4];
#pragma unroll
  for (int m = 0; m < 4; ++m)
#pragma unroll
    for (int n = 0; n < 4; ++n) acc[m][n] = zero;

  auto STAGE = [&](int bs, int k0) {
#pragma unroll
    for (int i = 0; i < 4; ++i) {
      int c = i * 256 + tid;
      int row = c >> 3, slot = c & 7;
      int srcSlot = slot ^ (row & 7);
      gld16(Ab + (size_t)row * lda + k0 + srcSlot * 8, &la[bs][(i * 256 + wave * 64) * 8]);
      gld16(Bb + (size_t)row * ldb + k0 + srcSlot * 8, &lb[bs][(i * 256 + wave * 64) * 8]);
    }
  };

  STAGE(0, 0);
  __syncthreads();
  int cur = 0;
  for (int k0 = 0; k0 < K; k0 += 64) {
    if (k0 + 64 < K) STAGE(cur ^ 1, k0 + 64);
    const char* lac = (const char*)la[cur];
    const char* lbc = (const char*)lb[cur];
#pragma unroll
    for (int kk = 0; kk < 2; ++kk) {
      const int colByte = (kk * 32 + g * 8) * 2;
      bf16x8 af[4], bfr[4];
#pragma unroll
      for (int m = 0; m < 4; ++m) {
        int row = wr * 64 + m * 16 + fr;
        af[m] = *(const bf16x8*)(lac + ((row * 128 + colByte) ^ ((row & 7) << 4)));
      }
#pragma unroll
      for (int n = 0; n < 4; ++n) {
        int row = wc * 64 + n * 16 + fr;
        bfr[n] = *(const bf16x8*)(lbc + ((row * 128 + colByte) ^ ((row & 7) << 4)));
      }
#pragma unroll
      for (int m = 0; m < 4; ++m)
#pragma unroll
        for (int n = 0; n < 4; ++n)
          acc[m][n] = __builtin_amdgcn_mfma_f32_16x16x32_bf16(af[m], bfr[n], acc[m][n], 0, 0, 0);
    }
    __syncthreads();
    cur ^= 1;
  }

#pragma unroll
  for (int n = 0; n < 4; ++n) {
    const int col = wc * 64 + n * 16 + fr;
    const size_t gcol = col0 + col;
    float bvv;
    if (EPI == 4) bvv = (gcol < 2048) ? bias[gcol] : resid[gcol - 2048];
    else bvv = bias[z * biasBatch + gcol];
#pragma unroll
    for (int m = 0; m < 4; ++m) {
#pragma unroll
      for (int r = 0; r < 4; ++r) {
        const int row = wr * 64 + m * 16 + g * 4 + r;
        const float val = acc[m][n][r] + bvv;
        const size_t grow = row0 + row;
        if (EPI == 0) {
          Cb[(size_t)z * cBatch + grow * ldc + gcol] = f2bf(val);
        } else if (EPI == 4) {
          if (gcol < 2048) {
            const int hh = (int)(gcol >> 8), dd = (int)(gcol & 255);
            Cb[(size_t)hh * (M_ * D_) + (size_t)(dd >> 3) * (M_ * 8) + grow * 8 + (dd & 7)] = f2bf(val);
          } else {
            const size_t g2 = gcol - 2048;
            const int hh = (int)(g2 >> 8), dd = (int)(g2 & 255);
            Cb[(size_t)H_ * (M_ * D_) + (size_t)hh * (M_ * D_) +
               (grow >> 3) * (D_ * 8) + (size_t)dd * 8 + (grow & 7)] = f2bf(val);
          }
        } else {
          Cf[grow * ldc + gcol] = val + resid[grow * ldc + gcol];
        }
      }
    }
  }
}

// ---------------- flash attention, KV-split x2 ----------------
// 512 blocks: h=bid&7 (XCD-local head), xt=(bid>>3)&31 (q-tile), s=bid>>8 (m-half).
// 4 waves x 32 q-rows, MFMA 32x32x16, swapped QK^T, KVBLK=32 dbuf.
// Outputs per (s,h,xt,wave): normalized f16 partial r'[256 d][32 q] + f32 (m,l).
__global__ __launch_bounds__(256, 2) void k_attn2(
    const u16* __restrict__ q, const u16* __restrict__ k2,
    const u16* __restrict__ v2, const u32* __restrict__ mw,
    _Float16* __restrict__ pr, float* __restrict__ pml)
{
  __shared__ u16 smem[32768];  // 64 KB = 2 buf x (16KB K + 16KB V)
  const int tid = threadIdx.x;
  const int lane = tid & 63, wave = tid >> 6;
  const int hi = lane >> 5, col = lane & 31;
  const int h = blockIdx.x & 7;
  const int xt = (blockIdx.x >> 3) & 31;
  const int s = blockIdx.x >> 8;
  const int n0w = xt * 128 + wave * 32;
  const float L2E = 1.44269504f;

  const u16* kh = k2 + (size_t)h * (M_ * D_);
  const u16* vh = v2 + (size_t)h * (M_ * D_);

  bf16x8 qf[16];
  {
    const u16* qp = q + ((size_t)h * N_ + n0w + col) * D_ + hi * 8;
#pragma unroll
    for (int dc = 0; dc < 16; ++dc) qf[dc] = *(const bf16x8*)(qp + dc * 16);
  }

  f32x16 racc[8];
#pragma unroll
  for (int i = 0; i < 8; ++i)
#pragma unroll
    for (int e = 0; e < 16; ++e) racc[i][e] = 0.f;

  float mrow = -3e38f, lrow = 0.f;
  const bool useMask = (h >= 4);
  const u32* mp = mw + (n0w + col);

  auto STAGE = [&](int bs, int m0) {
    u16* lkb = smem + bs * 16384;
    u16* lvb = lkb + 8192;
#pragma unroll
    for (int i = 0; i < 4; ++i) {
      int c = i * 256 + tid;
      gld16(kh + (size_t)(c >> 5) * (M_ * 8) + (size_t)(m0 + (c & 31)) * 8,
            lkb + (i * 256 + wave * 64) * 8);
      gld16(vh + (size_t)(c >> 8) * (D_ * 8) + (size_t)m0 * 256 + (size_t)(c & 255) * 8,
            lvb + (i * 256 + wave * 64) * 8);
    }
  };

  const int it0 = s * 64, it1 = it0 + 64;
  STAGE(0, it0 * 32);
  __syncthreads();
  int cur = 0;

  for (int it = it0; it < it1; ++it) {
    const int m0 = it * 32;
    if (it + 1 < it1) STAGE(cur ^ 1, m0 + 32);
    u32 mword = 0xFFFFFFFFu;
    if (useMask) mword = mp[(size_t)(m0 >> 5) * N_];

    const char* lkb = (const char*)smem + cur * 32768;
    const char* lvb = lkb + 16384;

    // ---- QK^T ----
    f32x16 sA, sB;
#pragma unroll
    for (int e = 0; e < 16; ++e) { sA[e] = 0.f; sB[e] = 0.f; }
#pragma unroll
    for (int dc = 0; dc < 16; dc += 2) {
      bf16x8 a0 = *(const bf16x8*)(lkb + dc * 1024 + lane * 16);
      bf16x8 a1 = *(const bf16x8*)(lkb + dc * 1024 + 1024 + lane * 16);
      sA = __builtin_amdgcn_mfma_f32_32x32x16_bf16(a0, qf[dc], sA, 0, 0, 0);
      sB = __builtin_amdgcn_mfma_f32_32x32x16_bf16(a1, qf[dc + 1], sB, 0, 0, 0);
    }
    f32x16 sv = sA + sB;

    if (useMask) {
      u32 mm = mword >> (hi * 4);
#pragma unroll
      for (int r = 0; r < 16; ++r)
        if (!((mm >> ((r & 3) + 8 * (r >> 2))) & 1u)) sv[r] -= 1e9f;
    }

    // ---- online softmax ----
    float pm = sv[0];
#pragma unroll
    for (int r = 1; r < 16; ++r) pm = fmaxf(pm, sv[r]);
    pm = fmaxf(pm, __shfl_xor(pm, 32));

    if (!__all(pm <= mrow + 8.f)) {          // defer-max
      float mnew = fmaxf(mrow, pm);
      float rs = __builtin_exp2f((mrow - mnew) * L2E);
      lrow *= rs;
#pragma unroll
      for (int i = 0; i < 8; ++i)
#pragma unroll
        for (int e = 0; e < 16; ++e) racc[i][e] *= rs;
      mrow = mnew;
    }
    const float mL = mrow * L2E;
    float p[16];
    float ls = 0.f;
#pragma unroll
    for (int r = 0; r < 16; ++r) {
      p[r] = __builtin_exp2f(sv[r] * L2E - mL);
      ls += p[r];
    }
    ls += __shfl_xor(ls, 32);
    lrow += ls;

    // ---- PV ----
#pragma unroll
    for (int ks = 0; ks < 2; ++ks) {
      u32 a0 = cvtpk(p[8 * ks + 0], p[8 * ks + 1]);
      u32 a1 = cvtpk(p[8 * ks + 2], p[8 * ks + 3]);
      u32 b0 = cvtpk(p[8 * ks + 4], p[8 * ks + 5]);
      u32 b1 = cvtpk(p[8 * ks + 6], p[8 * ks + 7]);
      u32 sa0 = __shfl_xor(a0, 32), sa1 = __shfl_xor(a1, 32);
      u32 sb0 = __shfl_xor(b0, 32), sb1 = __shfl_xor(b1, 32);
      union { u32 w[4]; bf16x8 v; } bp;
      bp.w[0] = hi ? sb0 : a0;
      bp.w[1] = hi ? sb1 : a1;
      bp.w[2] = hi ? b0 : sa0;
      bp.w[3] = hi ? b1 : sa1;
      const char* lvk = lvb + ks * 8192 + hi * 4096 + col * 16;
#pragma unroll
      for (int ds = 0; ds < 8; ++ds) {
        bf16x8 av = *(const bf16x8*)(lvk + ds * 512);
        racc[ds] = __builtin_amdgcn_mfma_f32_32x32x16_bf16(av, bp.v, racc[ds], 0, 0, 0);
      }
    }
    __syncthreads();
    cur ^= 1;
  }

  // ---- epilogue: normalized f16 partials [d][q] + (m,l) ----
  _Float16* prw = pr + ((size_t)(s * 8 + h) * 128 + xt * 4 + wave) * 8192;
  const float inv = 1.f / lrow;
#pragma unroll
  for (int ds = 0; ds < 8; ++ds) {
#pragma unroll
    for (int e = 0; e < 16; ++e) {
      const int d = ds * 32 + (e & 3) + 8 * (e >> 2) + 4 * hi;
      prw[d * 32 + col] = (_Float16)(racc[ds][e] * inv);
    }
  }
  if (hi == 0) {
    const size_t mb = ((size_t)(s * 8 + h) * N_ + n0w + col) * 2;
    pml[mb] = mrow; pml[mb + 1] = lrow;
  }
}

// ---------------- attention split merge ----------------
// grid 1024: h=bid&7, wi=bid>>3 (q-group of 32). Combine two normalized
// partials with flash weights, transpose via LDS, coalesced bf16 store to cat.
__global__ __launch_bounds__(256) void k_attn_merge(
    const _Float16* __restrict__ pr, const float* __restrict__ pml,
    u16* __restrict__ cat)
{
  __shared__ u16 lt[8192];  // [32 q][256 d]
  const int t = threadIdx.x, q = t & 31, dg = t >> 5;
  const int h = blockIdx.x & 7, wi = blockIdx.x >> 3;
  const int n0 = wi * 32, n = n0 + q;
  const size_t b0 = ((size_t)h * 128 + wi) * 8192;
  const size_t b1 = ((size_t)(8 + h) * 128 + wi) * 8192;
  const size_t i0 = ((size_t)h * N_ + n) * 2;
  const size_t i1 = ((size_t)(8 + h) * N_ + n) * 2;
  const float m0 = pml[i0], l0 = pml[i0 + 1];
  const float m1 = pml[i1], l1 = pml[i1 + 1];
  const float mm = fmaxf(m0, m1);
  float w0 = l0 * __builtin_exp2f((m0 - mm) * 1.44269504f);
  float w1 = l1 * __builtin_exp2f((m1 - mm) * 1.44269504f);
  const float inv = 1.f / (w0 + w1);
  w0 *= inv; w1 *= inv;
#pragma unroll
  for (int j = 0; j < 32; ++j) {
    const int d = dg * 32 + j;
    const float r = (float)pr[b0 + (size_t)d * 32 + q] * w0 +
                    (float)pr[b1 + (size_t)d * 32 + q] * w1;
    lt[q * 256 + d] = f2bf(r);
  }
  __syncthreads();
#pragma unroll
  for (int p = 0; p < 4; ++p) {
    const int c = p * 256 + t, row = c >> 5, ch = c & 31;
    uint4 val = *(const uint4*)(lt + row * 256 + ch * 8);
    *(uint4*)(cat + (size_t)(n0 + row) * (H_ * D_) + (size_t)h * D_ + ch * 8) = val;
  }
}

// ---------------- host launcher ----------------
extern "C" void kernel_launch(void* const* d_in, const int* in_sizes, int n_in,
                              void* d_out, int out_size, void* d_ws, size_t ws_size,
                              hipStream_t stream) {
  const float* thisf = (const float*)d_in[0];
  const float* thatf = (const float*)d_in[1];
  const void* maskp = (const void*)d_in[2];
  const float* Wq = (const float*)d_in[3];
  const float* bq = (const float*)d_in[4];
  const float* Wk = (const float*)d_in[5];
  const float* bk = (const float*)d_in[6];
  const float* Wv = (const float*)d_in[7];
  const float* bv = (const float*)d_in[8];
  const float* Wo = (const float*)d_in[9];
  const float* bo = (const float*)d_in[10];
  float* outp = (float*)d_out;

  char* ws = (char*)d_ws;
  size_t o = 0;
  // live-late buffers first
  u16* wot  = (u16*)(ws + o); o += (size_t)2 * F_ * F_ * 2;        // 4 MB
  u16* qb   = (u16*)(ws + o); o += (size_t)H_ * N_ * D_ * 2;       // 16 MB
  u16* k2   = (u16*)(ws + o); o += (size_t)H_ * M_ * D_ * 2;       // 16 MB (v2 contiguous after)
  u16* v2   = (u16*)(ws + o); o += (size_t)H_ * M_ * D_ * 2;       // 16 MB
  u16* catb = (u16*)(ws + o); o += (size_t)N_ * 2 * F_ * 2;        // 16 MB
  u32* mw2  = (u32*)(ws + o); o += (size_t)(M_ / 32) * N_ * 4;     // 2 MB
  float* pml = (float*)(ws + o); o += (size_t)2 * H_ * N_ * 2 * 4; // 0.5 MB
  u32* mflag = (u32*)(ws + o); o += 256;
  // dead-before-attn buffers last; pr aliases them
  u16* thisb = (u16*)(ws + o); o += (size_t)N_ * F_ * 2;           // 8 MB
  u16* thatb = (u16*)(ws + o); o += (size_t)M_ * F_ * 2;           // 8 MB
  u16* wqt  = (u16*)(ws + o); o += (size_t)H_ * D_ * F_ * 2;       // 4 MB
  u16* wkt  = (u16*)(ws + o); o += (size_t)H_ * D_ * F_ * 2;       // 4 MB  (wvt contiguous after)
  u16* wvt  = (u16*)(ws + o); o += (size_t)H_ * D_ * F_ * 2;       // 4 MB
  _Float16* pr = (_Float16*)thisb;                                  // 32 MB alias (+4 MB past wvt)
  (void)ws_size; (void)in_sizes; (void)n_in; (void)out_size;

  // 0) mask: detect dtype, ballot-pack to [m/32][q]
  k_mask_detect<<<dim3(1), dim3(64), 0, stream>>>((const u32*)maskp, mflag);
  k_mask_pack2<<<dim3(N_ * (M_ / 64) / 4), dim3(256), 0, stream>>>(maskp, mflag, mw2);

  // 1) dtype conversions
  k_f32_to_bf16<<<dim3(N_ * F_ / 4 / 256), dim3(256), 0, stream>>>(thisf, thisb, N_ * F_ / 4);
  k_f32_to_bf16<<<dim3(M_ * F_ / 4 / 256), dim3(256), 0, stream>>>(thatf, thatb, M_ * F_ / 4);
  k_transpose_f32_bf16<<<dim3(F_ / 32, D_ / 32, H_), dim3(256), 0, stream>>>(Wq, wqt, F_, D_);
  k_transpose_f32_bf16<<<dim3(F_ / 32, D_ / 32, H_), dim3(256), 0, stream>>>(Wk, wkt, F_, D_);
  k_transpose_f32_bf16<<<dim3(F_ / 32, D_ / 32, H_), dim3(256), 0, stream>>>(Wv, wvt, F_, D_);
  k_transpose_f32_bf16<<<dim3(2 * F_ / 32, F_ / 32, 1), dim3(256), 0, stream>>>(Wo, wot, 2 * F_, F_);

  // 2) q projection (z-batched) and fused k|v projection (one big GEMM)
  k_gemm_nt<0><<<dim3(N_ / 128, D_ / 128, H_), dim3(256), 0, stream>>>(
      thisb, wqt, bq, nullptr, qb, nullptr, F_, F_, F_, D_,
      (size_t)0, (size_t)D_ * F_, (size_t)D_, (size_t)N_ * D_);
  k_gemm_nt<4><<<dim3(M_ / 128, 4096 / 128, 1), dim3(256), 0, stream>>>(
      thatb, wkt, bk, bv, k2, nullptr, F_, F_, F_, 0,
      (size_t)0, (size_t)0, (size_t)0, (size_t)0);

  // 3) flash attention, KV-split x2 -> f16 partials (aliases dead buffers)
  k_attn2<<<dim3(512), dim3(256), 0, stream>>>(qb, k2, v2, mw2, pr, pml);

  // 4) merge partials -> cat [N][H*D] bf16
  k_attn_merge<<<dim3(1024), dim3(256), 0, stream>>>(pr, pml, catb);

  // 5) out = cat @ Wo + bo + this   (f32 out)
  k_gemm_nt<3><<<dim3(N_ / 128, F_ / 128, 1), dim3(256), 0, stream>>>(
      catb, wot, bo, thisf, nullptr, outp, 2 * F_, 2 * F_, 2 * F_, F_,
      (size_t)0, (size_t)0, (size_t)0, (size_t)0);
}